// Round 1
// baseline (941.711 us; speedup 1.0000x reference)
//
#include <hip/hip_runtime.h>
#include <math.h>

#define TB 1024
#define HID 256

__device__ __forceinline__ float sigm(float x) { return 1.f / (1.f + expf(-x)); }

// ---------------- conv1: (1024,3,84,84) -> (1024,32,20,20), k8 s4, relu, x/255 folded ----------------
__global__ __launch_bounds__(256) void k_conv1(const float* __restrict__ img,
                                               const float* __restrict__ W,
                                               const float* __restrict__ B,
                                               float* __restrict__ out) {
    int g = blockIdx.x * 256 + threadIdx.x;      // 0..409599
    int im = g / 400;
    int pix = g - im * 400;
    int oy = pix / 20, ox = pix - (pix / 20) * 20;
    int cog = blockIdx.y * 8;                    // wave-uniform channel group
    float acc[8];
#pragma unroll
    for (int i = 0; i < 8; ++i) acc[i] = 0.f;
    const float* ibase = img + im * (3 * 84 * 84);
#pragma unroll
    for (int c = 0; c < 3; ++c) {
#pragma unroll
        for (int ky = 0; ky < 8; ++ky) {
            const float* row = ibase + (c * 84 + oy * 4 + ky) * 84 + ox * 4;
            float4 v0 = *(const float4*)(row);
            float4 v1 = *(const float4*)(row + 4);
            float in[8] = {v0.x, v0.y, v0.z, v0.w, v1.x, v1.y, v1.z, v1.w};
#pragma unroll
            for (int kx = 0; kx < 8; ++kx) {
#pragma unroll
                for (int co = 0; co < 8; ++co)
                    acc[co] += in[kx] * W[((cog + co) * 3 + c) * 64 + ky * 8 + kx];
            }
        }
    }
    const float s = 1.f / 255.f;
#pragma unroll
    for (int co = 0; co < 8; ++co) {
        float v = acc[co] * s + B[cog + co];
        out[((im * 32 + cog + co) * 20 + oy) * 20 + ox] = v > 0.f ? v : 0.f;
    }
}

// ---------------- conv2: (1024,32,20,20) -> (1024,64,9,9), k4 s2, relu ----------------
__global__ __launch_bounds__(256) void k_conv2(const float* __restrict__ in,
                                               const float* __restrict__ W,
                                               const float* __restrict__ B,
                                               float* __restrict__ out) {
    int g = blockIdx.x * 256 + threadIdx.x;      // 0..82943
    int im = g / 81;
    int pix = g - im * 81;
    int oy = pix / 9, ox = pix - (pix / 9) * 9;
    int cog = blockIdx.y * 8;
    float acc[8];
#pragma unroll
    for (int i = 0; i < 8; ++i) acc[i] = 0.f;
    const float* ibase = in + im * 12800;
    for (int ci = 0; ci < 32; ++ci) {
#pragma unroll
        for (int ky = 0; ky < 4; ++ky) {
            const float* row = ibase + (ci * 20 + oy * 2 + ky) * 20 + ox * 2;
            float2 v0 = *(const float2*)(row);
            float2 v1 = *(const float2*)(row + 2);
            float inv[4] = {v0.x, v0.y, v1.x, v1.y};
#pragma unroll
            for (int kx = 0; kx < 4; ++kx) {
#pragma unroll
                for (int co = 0; co < 8; ++co)
                    acc[co] += inv[kx] * W[(((cog + co) * 32 + ci) * 4 + ky) * 4 + kx];
            }
        }
    }
#pragma unroll
    for (int co = 0; co < 8; ++co) {
        float v = acc[co] + B[cog + co];
        out[((im * 64 + cog + co) * 9 + oy) * 9 + ox] = v > 0.f ? v : 0.f;
    }
}

// ---------------- conv3: (1024,64,9,9) -> (1024,64,7,7) flat, k3 s1, relu ----------------
__global__ __launch_bounds__(256) void k_conv3(const float* __restrict__ in,
                                               const float* __restrict__ W,
                                               const float* __restrict__ B,
                                               float* __restrict__ out) {
    int g = blockIdx.x * 256 + threadIdx.x;      // 0..50175
    int im = g / 49;
    int pix = g - im * 49;
    int oy = pix / 7, ox = pix - (pix / 7) * 7;
    int cog = blockIdx.y * 8;
    float acc[8];
#pragma unroll
    for (int i = 0; i < 8; ++i) acc[i] = 0.f;
    const float* ibase = in + im * 5184;
    for (int ci = 0; ci < 64; ++ci) {
#pragma unroll
        for (int ky = 0; ky < 3; ++ky) {
            const float* row = ibase + (ci * 81) + (oy + ky) * 9 + ox;
            float i0 = row[0], i1 = row[1], i2 = row[2];
            float inv[3] = {i0, i1, i2};
#pragma unroll
            for (int kx = 0; kx < 3; ++kx) {
#pragma unroll
                for (int co = 0; co < 8; ++co)
                    acc[co] += inv[kx] * W[(((cog + co) * 64 + ci) * 3 + ky) * 3 + kx];
            }
        }
    }
#pragma unroll
    for (int co = 0; co < 8; ++co) {
        float v = acc[co] + B[cog + co];
        // flatten layout: ch*49 + pix
        out[im * 3136 + (cog + co) * 49 + pix] = v > 0.f ? v : 0.f;
    }
}

// ---------------- FC: feat = relu(a3[1024,3136] @ Wfc^T[3136,512] + bfc) ----------------
__global__ __launch_bounds__(256) void k_fc(const float* __restrict__ X,
                                            const float* __restrict__ W,
                                            const float* __restrict__ B,
                                            float* __restrict__ out) {
    int lane = threadIdx.x & 63;
    int wv = threadIdx.x >> 6;
    int m0 = blockIdx.x * 8;
    int n0 = blockIdx.y * 32 + wv * 8;
    float acc[64];
#pragma unroll
    for (int i = 0; i < 64; ++i) acc[i] = 0.f;
    for (int kk = 0; kk < 49; ++kk) {
        int k = kk * 64 + lane;
        float xv[8], wvv[8];
#pragma unroll
        for (int i = 0; i < 8; ++i) xv[i] = X[(m0 + i) * 3136 + k];
#pragma unroll
        for (int i = 0; i < 8; ++i) wvv[i] = W[(n0 + i) * 3136 + k];
#pragma unroll
        for (int mi = 0; mi < 8; ++mi)
#pragma unroll
            for (int ni = 0; ni < 8; ++ni)
                acc[mi * 8 + ni] += xv[mi] * wvv[ni];
    }
    float r = 0.f;
#pragma unroll
    for (int i = 0; i < 64; ++i) {
        float s = acc[i];
        s += __shfl_xor(s, 1); s += __shfl_xor(s, 2); s += __shfl_xor(s, 4);
        s += __shfl_xor(s, 8); s += __shfl_xor(s, 16); s += __shfl_xor(s, 32);
        if (lane == i) r = s;
    }
    int mi = lane >> 3, ni = lane & 7;
    float v = r + B[n0 + ni];
    out[(m0 + mi) * 512 + (n0 + ni)] = v > 0.f ? v : 0.f;
}

// ---------------- gx = feat @ W_ih[:, :512]^T + W_ih[:,512+act] + b_ih + b_hh ----------------
__global__ __launch_bounds__(256) void k_gx(const float* __restrict__ X,   // feat 1024x512
                                            const float* __restrict__ Wih, // 1024x517
                                            const float* __restrict__ bih,
                                            const float* __restrict__ bhh,
                                            const int* __restrict__ act,
                                            float* __restrict__ out) {
    int lane = threadIdx.x & 63;
    int wv = threadIdx.x >> 6;
    int m0 = blockIdx.x * 8;
    int n0 = blockIdx.y * 32 + wv * 8;
    float acc[64];
#pragma unroll
    for (int i = 0; i < 64; ++i) acc[i] = 0.f;
    for (int kk = 0; kk < 8; ++kk) {
        int k = kk * 64 + lane;
        float xv[8], wvv[8];
#pragma unroll
        for (int i = 0; i < 8; ++i) xv[i] = X[(m0 + i) * 512 + k];
#pragma unroll
        for (int i = 0; i < 8; ++i) wvv[i] = Wih[(n0 + i) * 517 + k];
#pragma unroll
        for (int mi = 0; mi < 8; ++mi)
#pragma unroll
            for (int ni = 0; ni < 8; ++ni)
                acc[mi * 8 + ni] += xv[mi] * wvv[ni];
    }
    float r = 0.f;
#pragma unroll
    for (int i = 0; i < 64; ++i) {
        float s = acc[i];
        s += __shfl_xor(s, 1); s += __shfl_xor(s, 2); s += __shfl_xor(s, 4);
        s += __shfl_xor(s, 8); s += __shfl_xor(s, 16); s += __shfl_xor(s, 32);
        if (lane == i) r = s;
    }
    int mi = lane >> 3, ni = lane & 7;
    int m = m0 + mi, n = n0 + ni;
    int a = act[m];
    float v = r + Wih[n * 517 + 512 + a] + bih[n] + bhh[n];
    out[m * 1024 + n] = v;
}

// ---------------- one LSTM step: g = gx[t] + (h*mask) @ Whh^T ; gates ; write c,h ----------------
__global__ __launch_bounds__(256) void k_lstm_step(int t,
                                                   const float* __restrict__ hsrc,
                                                   const float* __restrict__ csrc,
                                                   float* __restrict__ cdst,
                                                   const float* __restrict__ gx,
                                                   const float* __restrict__ Whh, // 1024x256
                                                   const float* __restrict__ done,
                                                   float* __restrict__ hs) {
    int lane = threadIdx.x & 63;
    int Wv = (blockIdx.x * 256 + threadIdx.x) >> 6;   // 0..2047
    int bp = Wv >> 7;                                  // 0..15
    int np = Wv & 127;                                 // 0..127
    int b0 = bp * 2, n0 = np * 2;
    float mb0 = 1.f - done[t * 32 + b0];
    float mb1 = 1.f - done[t * 32 + b0 + 1];
    float acc[16];
#pragma unroll
    for (int i = 0; i < 16; ++i) acc[i] = 0.f;
#pragma unroll
    for (int it = 0; it < 4; ++it) {
        int k = it * 64 + lane;
        float h0v = hsrc[b0 * 256 + k] * mb0;
        float h1v = hsrc[(b0 + 1) * 256 + k] * mb1;
#pragma unroll
        for (int p = 0; p < 2; ++p) {
#pragma unroll
            for (int g2 = 0; g2 < 4; ++g2) {
                float wv = Whh[(g2 * 256 + n0 + p) * 256 + k];
                acc[(0 * 2 + p) * 4 + g2] += h0v * wv;
                acc[(1 * 2 + p) * 4 + g2] += h1v * wv;
            }
        }
    }
    float gate[4] = {0.f, 0.f, 0.f, 0.f};
#pragma unroll
    for (int bi = 0; bi < 2; ++bi) {
#pragma unroll
        for (int p = 0; p < 2; ++p) {
#pragma unroll
            for (int g2 = 0; g2 < 4; ++g2) {
                float s = acc[(bi * 2 + p) * 4 + g2];
                s += __shfl_xor(s, 1); s += __shfl_xor(s, 2); s += __shfl_xor(s, 4);
                s += __shfl_xor(s, 8); s += __shfl_xor(s, 16); s += __shfl_xor(s, 32);
                if ((lane & 3) == bi * 2 + p) gate[g2] = s;
            }
        }
    }
    if (lane < 4) {
        int bi = lane >> 1, p = lane & 1;
        int b = b0 + bi, n = n0 + p;
        int row = t * 32 + b;
        float gi = gate[0] + gx[row * 1024 + 0 * 256 + n];
        float gf = gate[1] + gx[row * 1024 + 1 * 256 + n];
        float gg = gate[2] + gx[row * 1024 + 2 * 256 + n];
        float go = gate[3] + gx[row * 1024 + 3 * 256 + n];
        float mb = bi ? mb1 : mb0;
        float cm = csrc[b * 256 + n] * mb;
        float cn = sigm(gf) * cm + sigm(gi) * tanhf(gg);
        float hn = sigm(go) * tanhf(cn);
        cdst[b * 256 + n] = cn;
        hs[t * 8192 + b * 256 + n] = hn;
    }
}

// ---------------- heads: logits = tanh(h@Wp1^T+bp1)@Wp2^T+bp2 ; v similarly ; copy hT,cT ----------------
__global__ __launch_bounds__(256) void k_heads(const float* __restrict__ hs,
                                               const float* __restrict__ cb,
                                               const float* __restrict__ Wp1, const float* __restrict__ bp1,
                                               const float* __restrict__ Wp2, const float* __restrict__ bp2,
                                               const float* __restrict__ Wv1, const float* __restrict__ bv1,
                                               const float* __restrict__ Wv2, const float* __restrict__ bv2,
                                               float* __restrict__ out) {
    int lane = threadIdx.x & 63;
    int m = blockIdx.x * 4 + (threadIdx.x >> 6);   // 0..1023
    const float4* hv = (const float4*)(hs + m * 256);
    const float4* wp = (const float4*)(Wp1 + lane * 256);
    const float4* wq = (const float4*)(Wv1 + lane * 256);
    float ap = 0.f, av = 0.f;
#pragma unroll 8
    for (int k = 0; k < 64; ++k) {
        float4 h4 = hv[k];
        float4 p4 = wp[k];
        float4 q4 = wq[k];
        ap += h4.x * p4.x + h4.y * p4.y + h4.z * p4.z + h4.w * p4.w;
        av += h4.x * q4.x + h4.y * q4.y + h4.z * q4.z + h4.w * q4.w;
    }
    float hp = tanhf(ap + bp1[lane]);
    float hq = tanhf(av + bv1[lane]);
#pragma unroll
    for (int j = 0; j < 5; ++j) {
        float s = hp * Wp2[j * 64 + lane];
        s += __shfl_xor(s, 1); s += __shfl_xor(s, 2); s += __shfl_xor(s, 4);
        s += __shfl_xor(s, 8); s += __shfl_xor(s, 16); s += __shfl_xor(s, 32);
        if (lane == 0) out[m * 5 + j] = s + bp2[j];
    }
    float s = hq * Wv2[lane];
    s += __shfl_xor(s, 1); s += __shfl_xor(s, 2); s += __shfl_xor(s, 4);
    s += __shfl_xor(s, 8); s += __shfl_xor(s, 16); s += __shfl_xor(s, 32);
    if (lane == 0) out[5120 + m] = s + bv2[0];

    int g = blockIdx.x * 256 + threadIdx.x;
    if (g < 8192) {
        out[6144 + g] = hs[31 * 8192 + g];          // hT
        out[6144 + 8192 + g] = cb[g];               // cT
    }
}

extern "C" void kernel_launch(void* const* d_in, const int* in_sizes, int n_in,
                              void* d_out, int out_size, void* d_ws, size_t ws_size,
                              hipStream_t stream) {
    const float* image = (const float*)d_in[0];
    const int*   act   = (const int*)d_in[1];
    const float* done  = (const float*)d_in[2];
    const float* h0    = (const float*)d_in[3];
    const float* c0    = (const float*)d_in[4];
    const float* W1    = (const float*)d_in[5];
    const float* b1    = (const float*)d_in[6];
    const float* W2    = (const float*)d_in[7];
    const float* b2    = (const float*)d_in[8];
    const float* W3    = (const float*)d_in[9];
    const float* b3    = (const float*)d_in[10];
    const float* Wfc   = (const float*)d_in[11];
    const float* bfc   = (const float*)d_in[12];
    const float* Wih   = (const float*)d_in[13];
    const float* Whh   = (const float*)d_in[14];
    const float* bih   = (const float*)d_in[15];
    const float* bhh   = (const float*)d_in[16];
    const float* Wp1   = (const float*)d_in[17];
    const float* bp1   = (const float*)d_in[18];
    const float* Wp2   = (const float*)d_in[19];
    const float* bp2   = (const float*)d_in[20];
    const float* Wv1   = (const float*)d_in[21];
    const float* bv1   = (const float*)d_in[22];
    const float* Wv2   = (const float*)d_in[23];
    const float* bv2   = (const float*)d_in[24];
    float* out = (float*)d_out;
    float* ws = (float*)d_ws;

    // workspace layout (floats); a3/feat/gx/hs/c_buf overlap dead a1
    float* a2   = ws;                    // 5,308,416
    float* a1   = ws + 5308416;          // 13,107,200
    float* a3   = ws + 5308416;          // 3,211,264 (reuses a1 after conv2)
    float* feat = ws + 8519680;          // 524,288
    float* gx   = ws + 9043968;          // 1,048,576
    float* hs   = ws + 10092544;         // 262,144
    float* cb   = ws + 10354688;         // 8,192

    k_conv1<<<dim3(1600, 4), 256, 0, stream>>>(image, W1, b1, a1);
    k_conv2<<<dim3(324, 8), 256, 0, stream>>>(a1, W2, b2, a2);
    k_conv3<<<dim3(196, 8), 256, 0, stream>>>(a2, W3, b3, a3);
    k_fc<<<dim3(128, 16), 256, 0, stream>>>(a3, Wfc, bfc, feat);
    k_gx<<<dim3(128, 32), 256, 0, stream>>>(feat, Wih, bih, bhh, act, gx);
    for (int t = 0; t < 32; ++t) {
        const float* hsrc = (t == 0) ? h0 : (hs + (t - 1) * 8192);
        const float* csrc = (t == 0) ? c0 : cb;
        k_lstm_step<<<512, 256, 0, stream>>>(t, hsrc, csrc, cb, gx, Whh, done, hs);
    }
    k_heads<<<256, 256, 0, stream>>>(hs, cb, Wp1, bp1, Wp2, bp2, Wv1, bv1, Wv2, bv2, out);
}